// Round 7
// baseline (186.214 us; speedup 1.0000x reference)
//
#include <hip/hip_runtime.h>
#include <math.h>

#define S_LEN 2048
#define E_DIM 512
#define NE (S_LEN * E_DIM)
#define H_NUM 8
#define WH 32
#define NOFF 65
#define PROW (H_NUM * NOFF) /* 520 */
#define PN (S_LEN * PROW)

typedef float f32x4 __attribute__((ext_vector_type(4)));
typedef short short8 __attribute__((ext_vector_type(8)));

__device__ __forceinline__ unsigned short f2bf(float f) {
    union { float f; unsigned u; } cv; cv.f = f;
    unsigned u = cv.u;
    u += 0x7fffu + ((u >> 16) & 1u);   // RNE
    return (unsigned short)(u >> 16);
}
__device__ __forceinline__ unsigned pk2(float x, float y) {
    return (unsigned)f2bf(x) | ((unsigned)f2bf(y) << 16);
}

// ---------------------------------------------------------------------------
// qkv (proven R3): C = (x@W + bias)*scale, in-kernel bf16 cast, 64x64 tiles.
// ---------------------------------------------------------------------------
__device__ __forceinline__ void mfma_gemm_f32(
    const float* __restrict__ A, const float* __restrict__ W,
    const float* __restrict__ bias, float* __restrict__ C,
    float scale, int m0, int n0)
{
    __shared__ unsigned short As[64 * 40];
    __shared__ unsigned short Bs[64 * 40];
    const int tid = threadIdx.x;
    const int lane = tid & 63, wave = tid >> 6;
    const int quad = lane >> 4, l16 = lane & 15;
    const int wr = (wave >> 1) * 32, wc = (wave & 1) * 32;
    const int ar = tid >> 2, ac = (tid & 3) * 8;
    const int bn = tid & 63, bk0 = (tid >> 6) * 8;

    f32x4 acc00 = {0.f,0.f,0.f,0.f}, acc01 = acc00, acc10 = acc00, acc11 = acc00;

    for (int kk = 0; kk < E_DIM; kk += 32) {
        float4 a0 = *(const float4*)(A + (size_t)(m0 + ar) * E_DIM + kk + ac);
        float4 a1 = *(const float4*)(A + (size_t)(m0 + ar) * E_DIM + kk + ac + 4);
        float b[8];
#pragma unroll
        for (int j = 0; j < 8; ++j)
            b[j] = W[(size_t)(kk + bk0 + j) * E_DIM + n0 + bn];
        __syncthreads();
        uint4 ap; ap.x = pk2(a0.x, a0.y); ap.y = pk2(a0.z, a0.w);
        ap.z = pk2(a1.x, a1.y); ap.w = pk2(a1.z, a1.w);
        *(uint4*)(As + ar * 40 + ac) = ap;
        uint4 bp; bp.x = pk2(b[0], b[1]); bp.y = pk2(b[2], b[3]);
        bp.z = pk2(b[4], b[5]); bp.w = pk2(b[6], b[7]);
        *(uint4*)(Bs + bn * 40 + bk0) = bp;
        __syncthreads();
        short8 fa0 = *(const short8*)(As + (wr + l16) * 40 + quad * 8);
        short8 fa1 = *(const short8*)(As + (wr + 16 + l16) * 40 + quad * 8);
        short8 fb0 = *(const short8*)(Bs + (wc + l16) * 40 + quad * 8);
        short8 fb1 = *(const short8*)(Bs + (wc + 16 + l16) * 40 + quad * 8);
        acc00 = __builtin_amdgcn_mfma_f32_16x16x32_bf16(fa0, fb0, acc00, 0, 0, 0);
        acc01 = __builtin_amdgcn_mfma_f32_16x16x32_bf16(fa0, fb1, acc01, 0, 0, 0);
        acc10 = __builtin_amdgcn_mfma_f32_16x16x32_bf16(fa1, fb0, acc10, 0, 0, 0);
        acc11 = __builtin_amdgcn_mfma_f32_16x16x32_bf16(fa1, fb1, acc11, 0, 0, 0);
    }

#pragma unroll
    for (int mi = 0; mi < 2; ++mi) {
#pragma unroll
        for (int ni = 0; ni < 2; ++ni) {
            f32x4 a = (mi == 0) ? ((ni == 0) ? acc00 : acc01)
                                : ((ni == 0) ? acc10 : acc11);
            int n = n0 + wc + ni * 16 + l16;
            float bval = bias[n];
#pragma unroll
            for (int r = 0; r < 4; ++r) {
                int m = m0 + wr + mi * 16 + quad * 4 + r;
                C[(size_t)m * E_DIM + n] = (a[r] + bval) * scale;
            }
        }
    }
}

__global__ __launch_bounds__(256)
void qkv_gemm(const float* __restrict__ x,
              const float* __restrict__ Wq, const float* __restrict__ bq,
              const float* __restrict__ Wk, const float* __restrict__ bk,
              const float* __restrict__ Wv, const float* __restrict__ bv,
              float* __restrict__ q, float* __restrict__ k, float* __restrict__ v)
{
    const float* W; const float* b; float* o; float sc;
    if (blockIdx.z == 0)      { W = Wq; b = bq; o = q; sc = 0.125f; }
    else if (blockIdx.z == 1) { W = Wk; b = bk; o = k; sc = 1.0f; }
    else                      { W = Wv; b = bv; o = v; sc = 1.0f; }
    mfma_gemm_f32(x, W, b, o, sc, blockIdx.y * 64, blockIdx.x * 64);
}

// ---------------------------------------------------------------------------
// scores (proven R3): block = 32 dst x 1 head. P exact-zero off-band.
// ---------------------------------------------------------------------------
#define SDN 32
__global__ __launch_bounds__(256)
void scores_kernel(const float* __restrict__ q, const float* __restrict__ k,
                   const float* __restrict__ amask, float* __restrict__ P)
{
    const int i0 = blockIdx.x * SDN;
    const int h  = blockIdx.y;
    const int tid = threadIdx.x;
    __shared__ float ks[96 * 68];
    __shared__ float am[96];
    __shared__ float sc[SDN * 66];
    __shared__ float smx[SDN], sidn[SDN];

    for (int e = tid; e < 96 * 16; e += 256) {
        int lr = e >> 4, c4 = e & 15;
        int j = i0 - WH + lr;
        int jc = min(max(j, 0), S_LEN - 1);
        *(float4*)(ks + lr * 68 + c4 * 4) =
            *(const float4*)(k + (size_t)jc * E_DIM + h * 64 + c4 * 4);
    }
    if (tid < 96) {
        int j = i0 - WH + tid;
        am[tid] = (j >= 0 && j < S_LEN) ? amask[j] : -1.0f;
    }

    const int dst = tid >> 3;
    const int og  = tid & 7;
    float4 qreg[16];
    {
        const float4* qrow = (const float4*)(q + (size_t)(i0 + dst) * E_DIM + h * 64);
#pragma unroll
        for (int t = 0; t < 16; ++t) qreg[t] = qrow[t];
    }
    __syncthreads();

    for (int off = og; off < NOFF; off += 8) {
        int j = i0 + dst + off - WH;
        float s;
        if (j < 0 || j >= S_LEN) {
            s = -INFINITY;
        } else {
            int lr = dst + off;
            const float4* kr = (const float4*)(ks + lr * 68);
            float acc = 0.f;
#pragma unroll
            for (int t = 0; t < 16; ++t) {
                float4 a = qreg[t], bb = kr[t];
                acc += a.x * bb.x + a.y * bb.y + a.z * bb.z + a.w * bb.w;
            }
            s = (am[lr] >= 0.f) ? acc : -1e9f;
        }
        sc[dst * 66 + off] = s;
    }
    __syncthreads();

    if (tid < SDN) {
        float mx = -INFINITY;
        for (int o = 0; o < NOFF; ++o) mx = fmaxf(mx, sc[tid * 66 + o]);
        float dn = 0.f;
        for (int o = 0; o < NOFF; ++o) dn += expf(sc[tid * 66 + o] - mx);
        smx[tid] = mx; sidn[tid] = 1.f / dn;
    }
    __syncthreads();

    for (int e = tid; e < SDN * NOFF; e += 256) {
        int d = e / NOFF, off = e - d * NOFF;
        float pv = expf(sc[d * 66 + off] - smx[d]) * sidn[d];
        P[(size_t)(i0 + d) * PROW + h * NOFF + off] = pv;
    }
}

// ---------------------------------------------------------------------------
// diffuse2c: TWO diffusion steps, 32-col blocks for 2 blocks/CU occupancy.
// block = 64 out rows x 32 cols. grid (32, 16). LDS 79.4 KB.
// hs rows [i0-64,i0+128) (192), h1 mid rows [i0-32,i0+96) (128), ps same rows.
// ---------------------------------------------------------------------------
__global__ __launch_bounds__(512)
void diffuse2c(const float* __restrict__ hin, const float* __restrict__ v,
               const float* __restrict__ P, float* __restrict__ hout)
{
    const int i0 = blockIdx.x * 64;
    const int c0 = blockIdx.y * 32;       // global E column base
    const int h  = c0 >> 6;               // head of these 32 cols
    const int tid = threadIdx.x;
    __shared__ float hs[192 * 36];        // stride 36: 2-way max on b128
    __shared__ float h1[128 * 36];
    __shared__ float ps[128 * NOFF];

    for (int e = tid; e < 192 * 8; e += 512) {
        int lr = e >> 3, c4 = e & 7;
        int j = i0 - 64 + lr;
        int jc = min(max(j, 0), S_LEN - 1);
        *(float4*)(hs + lr * 36 + c4 * 4) =
            *(const float4*)(hin + (size_t)jc * E_DIM + c0 + c4 * 4);
    }
    for (int e = tid; e < 128 * NOFF; e += 512) {
        int mr = e / NOFF, o = e - mr * NOFF;
        int j = i0 - 32 + mr;
        int jc = min(max(j, 0), S_LEN - 1);
        ps[e] = P[(size_t)jc * PROW + h * NOFF + o];
    }
    __syncthreads();

    const int ci = tid & 7;               // float4 col index (8 x 4 = 32 cols)
    const int g  = tid >> 3;              // 64 groups

    // ---- step A: mid rows g*2, g*2+1 ----
    {
        float4 a0 = {0,0,0,0}, a1 = a0;
        const int mb = g * 2;
        for (int lr = 0; lr < 66; ++lr) {
            float4 hval = *(const float4*)(hs + (mb + lr) * 36 + ci * 4);
            if (lr <= 64) {
                float p = ps[mb * NOFF + lr];
                a0.x += p * hval.x; a0.y += p * hval.y; a0.z += p * hval.z; a0.w += p * hval.w;
            }
            int o1 = lr - 1;
            if ((unsigned)o1 <= 64u) {
                float p = ps[(mb + 1) * NOFF + o1];
                a1.x += p * hval.x; a1.y += p * hval.y; a1.z += p * hval.z; a1.w += p * hval.w;
            }
        }
#pragma unroll
        for (int r = 0; r < 2; ++r) {
            float4 a = r ? a1 : a0;
            int j = i0 - 32 + mb + r;
            int jc = min(max(j, 0), S_LEN - 1);
            float4 vv = *(const float4*)(v + (size_t)jc * E_DIM + c0 + ci * 4);
            float4 o;
            o.x = 0.9f * a.x + 0.1f * vv.x;
            o.y = 0.9f * a.y + 0.1f * vv.y;
            o.z = 0.9f * a.z + 0.1f * vv.z;
            o.w = 0.9f * a.w + 0.1f * vv.w;
            *(float4*)(h1 + (mb + r) * 36 + ci * 4) = o;
        }
    }
    __syncthreads();

    // ---- step B: out row g ----
    {
        float4 a = {0,0,0,0};
        for (int off = 0; off < NOFF; ++off) {
            float4 hval = *(const float4*)(h1 + (g + off) * 36 + ci * 4);
            float p = ps[(g + 32) * NOFF + off];
            a.x += p * hval.x; a.y += p * hval.y; a.z += p * hval.z; a.w += p * hval.w;
        }
        size_t base = (size_t)(i0 + g) * E_DIM + c0 + ci * 4;
        float4 vv = *(const float4*)(v + base);
        float4 o;
        o.x = 0.9f * a.x + 0.1f * vv.x;
        o.y = 0.9f * a.y + 0.1f * vv.y;
        o.z = 0.9f * a.z + 0.1f * vv.z;
        o.w = 0.9f * a.w + 0.1f * vv.w;
        *(float4*)(hout + base) = o;
    }
}

// ---------------------------------------------------------------------------
// oln2: diffusion step 5 + (h@Wo + bo + x) + LayerNorm, all fused.
// Block = 16 out rows x 512 cols, 512 threads, 128 blocks.
// Per kk chunk (32 cols of k == 32 cols of h, single head): stage hB[80][37]
// + v[16][32], compute h fp32 (same order as diffuse1 -> identical numerics),
// pack bf16 into As, then 4 MFMA per wave. P staged once (16 x 520).
// ---------------------------------------------------------------------------
__global__ __launch_bounds__(512)
void oln2(const float* __restrict__ hB, const float* __restrict__ v,
          const float* __restrict__ P, const float* __restrict__ Wo,
          const float* __restrict__ bo, const float* __restrict__ x,
          const float* __restrict__ g, const float* __restrict__ lb,
          float* __restrict__ out)
{
    __shared__ unsigned short As[16 * 40];     // 1280 B
    __shared__ unsigned short Bs[512 * 40];    // 40960 B
    __shared__ float hBs[80 * 37];             // 11840 B
    __shared__ float Ps[16 * PROW];            // 33280 B
    __shared__ float vs[16 * 32];              // 2048 B
    __shared__ float rsum[8][16], rsq[8][16];  // 1024 B  (total ~90.4 KB)
    const int tid = threadIdx.x;
    const int lane = tid & 63, wave = tid >> 6;
    const int quad = lane >> 4, l16 = lane & 15;
    const int m0 = blockIdx.x * 16;
    const int n = tid;

    // stage P rows m0..m0+16 (all heads) once
    for (int e = tid; e < 16 * PROW; e += 512)
        Ps[e] = P[(size_t)(m0 + e / PROW) * PROW + (e % PROW)];

    f32x4 acc[4];
#pragma unroll
    for (int t = 0; t < 4; ++t) acc[t] = (f32x4){0.f,0.f,0.f,0.f};

    for (int kk = 0; kk < E_DIM; kk += 32) {
        const int hd = kk >> 6;                // head of this chunk
        // global loads for this iter
        float4 hv4;
        {
            int lr = tid >> 3, c4 = tid & 7;   // 64 rows x 8 -- need 80 rows:
            // 512 threads cover 64 rows; rows 64..79 by threads 0..127 (2nd load)
            int j = m0 - 32 + lr;
            int jc = min(max(j, 0), S_LEN - 1);
            hv4 = *(const float4*)(hB + (size_t)jc * E_DIM + kk + c4 * 4);
        }
        float4 hv4b;
        if (tid < 128) {
            int lr = 64 + (tid >> 3), c4 = tid & 7;
            int j = m0 - 32 + lr;
            int jc = min(max(j, 0), S_LEN - 1);
            hv4b = *(const float4*)(hB + (size_t)jc * E_DIM + kk + c4 * 4);
        }
        float4 vv4;
        if (tid < 128)
            vv4 = *(const float4*)(v + (size_t)(m0 + (tid >> 3)) * E_DIM + kk + (tid & 7) * 4);
        float bcol[32];
#pragma unroll
        for (int j = 0; j < 32; ++j)
            bcol[j] = Wo[(size_t)(kk + j) * E_DIM + n];

        __syncthreads();   // prior iter's As/Bs/hBs/vs reads complete
        {
            int lr = tid >> 3, c4 = tid & 7;
            *(float4*)(hBs + lr * 37 + c4 * 4) = hv4;
        }
        if (tid < 128) {
            int lr = 64 + (tid >> 3), c4 = tid & 7;
            *(float4*)(hBs + lr * 37 + c4 * 4) = hv4b;
        }
        if (tid < 128)
            *(float4*)(vs + (tid >> 3) * 32 + (tid & 7) * 4) = vv4;
#pragma unroll
        for (int t = 0; t < 4; ++t) {
            uint4 bp;
            bp.x = pk2(bcol[t*8+0], bcol[t*8+1]); bp.y = pk2(bcol[t*8+2], bcol[t*8+3]);
            bp.z = pk2(bcol[t*8+4], bcol[t*8+5]); bp.w = pk2(bcol[t*8+6], bcol[t*8+7]);
            *(uint4*)(Bs + n * 40 + t * 8) = bp;
        }
        __syncthreads();

        // compute h[16][32] (fp32, off ascending -- matches diffuse1) -> As bf16
        if (tid < 256) {
            int r = tid >> 4, cp = (tid & 15) * 2;   // two columns cp, cp+1
            const float* pr = Ps + r * PROW + hd * NOFF;
            float a0 = 0.f, a1 = 0.f;
            for (int off = 0; off < NOFF; ++off) {
                float p = pr[off];
                a0 += p * hBs[(r + off) * 37 + cp];
                a1 += p * hBs[(r + off) * 37 + cp + 1];
            }
            float h0 = 0.9f * a0 + 0.1f * vs[r * 32 + cp];
            float h1 = 0.9f * a1 + 0.1f * vs[r * 32 + cp + 1];
            *(unsigned*)(As + r * 40 + cp) = pk2(h0, h1);
        }
        __syncthreads();

        short8 fa = *(const short8*)(As + l16 * 40 + quad * 8);
#pragma unroll
        for (int nt = 0; nt < 4; ++nt) {
            short8 fb = *(const short8*)(Bs + (wave * 64 + nt * 16 + l16) * 40 + quad * 8);
            acc[nt] = __builtin_amdgcn_mfma_f32_16x16x32_bf16(fa, fb, acc[nt], 0, 0, 0);
        }
    }

    // epilogue: bias + resid, LN
    float s[4] = {0.f,0.f,0.f,0.f}, s2[4] = {0.f,0.f,0.f,0.f};
#pragma unroll
    for (int nt = 0; nt < 4; ++nt) {
        int nc = wave * 64 + nt * 16 + l16;
        float bv = bo[nc];
#pragma unroll
        for (int r = 0; r < 4; ++r) {
            int m = m0 + quad * 4 + r;
            float vl = acc[nt][r] + bv + x[(size_t)m * E_DIM + nc];
            acc[nt][r] = vl;
            s[r] += vl; s2[r] += vl * vl;
        }
    }
#pragma unroll
    for (int o = 1; o < 16; o <<= 1) {
#pragma unroll
        for (int r = 0; r < 4; ++r) {
            s[r]  += __shfl_xor(s[r], o, 64);
            s2[r] += __shfl_xor(s2[r], o, 64);
        }
    }
    if (l16 == 0) {
#pragma unroll
        for (int r = 0; r < 4; ++r) {
            rsum[wave][quad * 4 + r] = s[r];
            rsq[wave][quad * 4 + r]  = s2[r];
        }
    }
    __syncthreads();
    float mu[4], rs[4];
#pragma unroll
    for (int r = 0; r < 4; ++r) {
        int rl = quad * 4 + r;
        float tot = 0.f, tot2 = 0.f;
#pragma unroll
        for (int w = 0; w < 8; ++w) { tot += rsum[w][rl]; tot2 += rsq[w][rl]; }
        float m_ = tot * (1.f / 512.f);
        float var = tot2 * (1.f / 512.f) - m_ * m_;
        mu[r] = m_; rs[r] = rsqrtf(var + 1e-12f);
    }
#pragma unroll
    for (int nt = 0; nt < 4; ++nt) {
        int nc = wave * 64 + nt * 16 + l16;
        float gv = g[nc], bbv = lb[nc];
#pragma unroll
        for (int r = 0; r < 4; ++r) {
            int m = m0 + quad * 4 + r;
            out[(size_t)m * E_DIM + nc] = (acc[nt][r] - mu[r]) * rs[r] * gv + bbv;
        }
    }
}

// ---------------------------------------------------------------------------
extern "C" void kernel_launch(void* const* d_in, const int* in_sizes, int n_in,
                              void* d_out, int out_size, void* d_ws, size_t ws_size,
                              hipStream_t stream)
{
    const float* x     = (const float*)d_in[0];
    const float* amask = (const float*)d_in[1];
    const float* Wq = (const float*)d_in[4];
    const float* bq = (const float*)d_in[5];
    const float* Wk = (const float*)d_in[6];
    const float* bk = (const float*)d_in[7];
    const float* Wv = (const float*)d_in[8];
    const float* bv = (const float*)d_in[9];
    const float* Wo = (const float*)d_in[10];
    const float* bo = (const float*)d_in[11];
    const float* lng = (const float*)d_in[12];
    const float* lnb = (const float*)d_in[13];
    float* out = (float*)d_out;

    float* ws = (float*)d_ws;
    float* q  = ws;
    float* k  = ws + (size_t)NE;
    float* v  = ws + (size_t)2 * NE;
    float* P  = ws + (size_t)3 * NE;
    float* hA = ws + (size_t)3 * NE + PN;
    float* hB = hA + (size_t)NE;

    qkv_gemm<<<dim3(8, 32, 3), 256, 0, stream>>>(x, Wq, bq, Wk, bk, Wv, bv, q, k, v);

    scores_kernel<<<dim3(64, 8), 256, 0, stream>>>(q, k, amask, P);

    diffuse2c<<<dim3(32, 16), 512, 0, stream>>>(v,  v, P, hA);  // steps 1-2
    diffuse2c<<<dim3(32, 16), 512, 0, stream>>>(hA, v, P, hB);  // steps 3-4

    oln2<<<128, 512, 0, stream>>>(hB, v, P, Wo, bo, x, lng, lnb, out); // step 5 + GEMM + LN
}

// Round 8
// 174.865 us; speedup vs baseline: 1.0649x; 1.0649x over previous
//
#include <hip/hip_runtime.h>
#include <math.h>

#define S_LEN 2048
#define E_DIM 512
#define NE (S_LEN * E_DIM)
#define H_NUM 8
#define WH 32
#define NOFF 65
#define PROW (H_NUM * NOFF) /* 520 */
#define PN (S_LEN * PROW)

typedef float f32x4 __attribute__((ext_vector_type(4)));
typedef short short8 __attribute__((ext_vector_type(8)));

__device__ __forceinline__ unsigned short f2bf(float f) {
    union { float f; unsigned u; } cv; cv.f = f;
    unsigned u = cv.u;
    u += 0x7fffu + ((u >> 16) & 1u);   // RNE
    return (unsigned short)(u >> 16);
}
__device__ __forceinline__ unsigned pk2(float x, float y) {
    return (unsigned)f2bf(x) | ((unsigned)f2bf(y) << 16);
}

// ---------------------------------------------------------------------------
// qkv (proven R3): C = (x@W + bias)*scale, in-kernel bf16 cast, 64x64 tiles.
// ---------------------------------------------------------------------------
__device__ __forceinline__ void mfma_gemm_f32(
    const float* __restrict__ A, const float* __restrict__ W,
    const float* __restrict__ bias, float* __restrict__ C,
    float scale, int m0, int n0)
{
    __shared__ unsigned short As[64 * 40];
    __shared__ unsigned short Bs[64 * 40];
    const int tid = threadIdx.x;
    const int lane = tid & 63, wave = tid >> 6;
    const int quad = lane >> 4, l16 = lane & 15;
    const int wr = (wave >> 1) * 32, wc = (wave & 1) * 32;
    const int ar = tid >> 2, ac = (tid & 3) * 8;
    const int bn = tid & 63, bk0 = (tid >> 6) * 8;

    f32x4 acc00 = {0.f,0.f,0.f,0.f}, acc01 = acc00, acc10 = acc00, acc11 = acc00;

    for (int kk = 0; kk < E_DIM; kk += 32) {
        float4 a0 = *(const float4*)(A + (size_t)(m0 + ar) * E_DIM + kk + ac);
        float4 a1 = *(const float4*)(A + (size_t)(m0 + ar) * E_DIM + kk + ac + 4);
        float b[8];
#pragma unroll
        for (int j = 0; j < 8; ++j)
            b[j] = W[(size_t)(kk + bk0 + j) * E_DIM + n0 + bn];
        __syncthreads();
        uint4 ap; ap.x = pk2(a0.x, a0.y); ap.y = pk2(a0.z, a0.w);
        ap.z = pk2(a1.x, a1.y); ap.w = pk2(a1.z, a1.w);
        *(uint4*)(As + ar * 40 + ac) = ap;
        uint4 bp; bp.x = pk2(b[0], b[1]); bp.y = pk2(b[2], b[3]);
        bp.z = pk2(b[4], b[5]); bp.w = pk2(b[6], b[7]);
        *(uint4*)(Bs + bn * 40 + bk0) = bp;
        __syncthreads();
        short8 fa0 = *(const short8*)(As + (wr + l16) * 40 + quad * 8);
        short8 fa1 = *(const short8*)(As + (wr + 16 + l16) * 40 + quad * 8);
        short8 fb0 = *(const short8*)(Bs + (wc + l16) * 40 + quad * 8);
        short8 fb1 = *(const short8*)(Bs + (wc + 16 + l16) * 40 + quad * 8);
        acc00 = __builtin_amdgcn_mfma_f32_16x16x32_bf16(fa0, fb0, acc00, 0, 0, 0);
        acc01 = __builtin_amdgcn_mfma_f32_16x16x32_bf16(fa0, fb1, acc01, 0, 0, 0);
        acc10 = __builtin_amdgcn_mfma_f32_16x16x32_bf16(fa1, fb0, acc10, 0, 0, 0);
        acc11 = __builtin_amdgcn_mfma_f32_16x16x32_bf16(fa1, fb1, acc11, 0, 0, 0);
    }

#pragma unroll
    for (int mi = 0; mi < 2; ++mi) {
#pragma unroll
        for (int ni = 0; ni < 2; ++ni) {
            f32x4 a = (mi == 0) ? ((ni == 0) ? acc00 : acc01)
                                : ((ni == 0) ? acc10 : acc11);
            int n = n0 + wc + ni * 16 + l16;
            float bval = bias[n];
#pragma unroll
            for (int r = 0; r < 4; ++r) {
                int m = m0 + wr + mi * 16 + quad * 4 + r;
                C[(size_t)m * E_DIM + n] = (a[r] + bval) * scale;
            }
        }
    }
}

__global__ __launch_bounds__(256)
void qkv_gemm(const float* __restrict__ x,
              const float* __restrict__ Wq, const float* __restrict__ bq,
              const float* __restrict__ Wk, const float* __restrict__ bk,
              const float* __restrict__ Wv, const float* __restrict__ bv,
              float* __restrict__ q, float* __restrict__ k, float* __restrict__ v)
{
    const float* W; const float* b; float* o; float sc;
    if (blockIdx.z == 0)      { W = Wq; b = bq; o = q; sc = 0.125f; }
    else if (blockIdx.z == 1) { W = Wk; b = bk; o = k; sc = 1.0f; }
    else                      { W = Wv; b = bv; o = v; sc = 1.0f; }
    mfma_gemm_f32(x, W, b, o, sc, blockIdx.y * 64, blockIdx.x * 64);
}

// ---------------------------------------------------------------------------
// scores_d1: scores + edge-softmax + diffusion STEP 1, fused.
// block = 32 dst x 1 head (512 blocks, 256 thr). After P is computed the
// k-tile LDS is dead; reload it with v rows and run the diffuse1 inner loop
// (same fp32 order as before -> identical numerics). Writes P and hA.
// ---------------------------------------------------------------------------
#define SDN 32
__global__ __launch_bounds__(256)
void scores_d1(const float* __restrict__ q, const float* __restrict__ k,
               const float* __restrict__ v, const float* __restrict__ amask,
               float* __restrict__ P, float* __restrict__ hA)
{
    const int i0 = blockIdx.x * SDN;
    const int h  = blockIdx.y;
    const int tid = threadIdx.x;
    __shared__ float ks[96 * 68];      // k rows [i0-32,i0+64); later v rows
    __shared__ float am[96];
    __shared__ float sc[SDN * 66];
    __shared__ float smx[SDN], sidn[SDN];
    __shared__ float ps[SDN * NOFF];   // P values of this block

    for (int e = tid; e < 96 * 16; e += 256) {
        int lr = e >> 4, c4 = e & 15;
        int j = i0 - WH + lr;
        int jc = min(max(j, 0), S_LEN - 1);
        *(float4*)(ks + lr * 68 + c4 * 4) =
            *(const float4*)(k + (size_t)jc * E_DIM + h * 64 + c4 * 4);
    }
    if (tid < 96) {
        int j = i0 - WH + tid;
        am[tid] = (j >= 0 && j < S_LEN) ? amask[j] : -1.0f;
    }

    const int dst = tid >> 3;
    const int og  = tid & 7;
    float4 qreg[16];
    {
        const float4* qrow = (const float4*)(q + (size_t)(i0 + dst) * E_DIM + h * 64);
#pragma unroll
        for (int t = 0; t < 16; ++t) qreg[t] = qrow[t];
    }
    __syncthreads();

    for (int off = og; off < NOFF; off += 8) {
        int j = i0 + dst + off - WH;
        float s;
        if (j < 0 || j >= S_LEN) {
            s = -INFINITY;
        } else {
            int lr = dst + off;
            const float4* kr = (const float4*)(ks + lr * 68);
            float acc = 0.f;
#pragma unroll
            for (int t = 0; t < 16; ++t) {
                float4 a = qreg[t], bb = kr[t];
                acc += a.x * bb.x + a.y * bb.y + a.z * bb.z + a.w * bb.w;
            }
            s = (am[lr] >= 0.f) ? acc : -1e9f;
        }
        sc[dst * 66 + off] = s;
    }
    __syncthreads();   // sc done; ks no longer read as k

    // overwrite ks with v rows [i0-32, i0+64) while row stats compute
    for (int e = tid; e < 96 * 16; e += 256) {
        int lr = e >> 4, c4 = e & 15;
        int j = i0 - WH + lr;
        int jc = min(max(j, 0), S_LEN - 1);
        *(float4*)(ks + lr * 68 + c4 * 4) =
            *(const float4*)(v + (size_t)jc * E_DIM + h * 64 + c4 * 4);
    }
    if (tid < SDN) {
        float mx = -INFINITY;
        for (int o = 0; o < NOFF; ++o) mx = fmaxf(mx, sc[tid * 66 + o]);
        float dn = 0.f;
        for (int o = 0; o < NOFF; ++o) dn += expf(sc[tid * 66 + o] - mx);
        smx[tid] = mx; sidn[tid] = 1.f / dn;
    }
    __syncthreads();

    for (int e = tid; e < SDN * NOFF; e += 256) {
        int d = e / NOFF, off = e - d * NOFF;
        float pv = expf(sc[d * 66 + off] - smx[d]) * sidn[d];
        P[(size_t)(i0 + d) * PROW + h * NOFF + off] = pv;
        ps[e] = pv;    // e == d*NOFF + off
    }
    __syncthreads();

    // diffusion step 1 for out rows i0..i0+31, head cols h (diffuse1 pattern)
    {
        const int ci = tid & 15;
        const int ob = (tid >> 4) * 2;     // 16 groups x 2 rows
        float4 a0 = {0,0,0,0}, a1 = a0;
        for (int lr = ob; lr < ob + 66; ++lr) {
            float4 hval = *(const float4*)(ks + lr * 68 + ci * 4);
            int o0 = lr - ob;
            if (o0 <= 64) {
                float p = ps[ob * NOFF + o0];
                a0.x += p * hval.x; a0.y += p * hval.y; a0.z += p * hval.z; a0.w += p * hval.w;
            }
            int o1 = o0 - 1;
            if ((unsigned)o1 <= 64u) {
                float p = ps[(ob + 1) * NOFF + o1];
                a1.x += p * hval.x; a1.y += p * hval.y; a1.z += p * hval.z; a1.w += p * hval.w;
            }
        }
#pragma unroll
        for (int r = 0; r < 2; ++r) {
            float4 a = r ? a1 : a0;
            float4 vv = *(const float4*)(ks + (WH + ob + r) * 68 + ci * 4); // v[i0+ob+r]
            float4 o;
            o.x = 0.9f * a.x + 0.1f * vv.x;
            o.y = 0.9f * a.y + 0.1f * vv.y;
            o.z = 0.9f * a.z + 0.1f * vv.z;
            o.w = 0.9f * a.w + 0.1f * vv.w;
            *(float4*)(hA + (size_t)(i0 + ob + r) * E_DIM + h * 64 + ci * 4) = o;
        }
    }
}

// ---------------------------------------------------------------------------
// diffuse2c (proven R7): TWO steps, 32-col blocks -> 2 blocks/CU.
// block = 64 out rows x 32 cols. grid (32, 16). LDS 79.4 KB.
// ---------------------------------------------------------------------------
__global__ __launch_bounds__(512)
void diffuse2c(const float* __restrict__ hin, const float* __restrict__ v,
               const float* __restrict__ P, float* __restrict__ hout)
{
    const int i0 = blockIdx.x * 64;
    const int c0 = blockIdx.y * 32;
    const int h  = c0 >> 6;
    const int tid = threadIdx.x;
    __shared__ float hs[192 * 36];
    __shared__ float h1[128 * 36];
    __shared__ float ps[128 * NOFF];

    for (int e = tid; e < 192 * 8; e += 512) {
        int lr = e >> 3, c4 = e & 7;
        int j = i0 - 64 + lr;
        int jc = min(max(j, 0), S_LEN - 1);
        *(float4*)(hs + lr * 36 + c4 * 4) =
            *(const float4*)(hin + (size_t)jc * E_DIM + c0 + c4 * 4);
    }
    for (int e = tid; e < 128 * NOFF; e += 512) {
        int mr = e / NOFF, o = e - mr * NOFF;
        int j = i0 - 32 + mr;
        int jc = min(max(j, 0), S_LEN - 1);
        ps[e] = P[(size_t)jc * PROW + h * NOFF + o];
    }
    __syncthreads();

    const int ci = tid & 7;
    const int g  = tid >> 3;

    // ---- step A: mid rows g*2, g*2+1 ----
    {
        float4 a0 = {0,0,0,0}, a1 = a0;
        const int mb = g * 2;
        for (int lr = 0; lr < 66; ++lr) {
            float4 hval = *(const float4*)(hs + (mb + lr) * 36 + ci * 4);
            if (lr <= 64) {
                float p = ps[mb * NOFF + lr];
                a0.x += p * hval.x; a0.y += p * hval.y; a0.z += p * hval.z; a0.w += p * hval.w;
            }
            int o1 = lr - 1;
            if ((unsigned)o1 <= 64u) {
                float p = ps[(mb + 1) * NOFF + o1];
                a1.x += p * hval.x; a1.y += p * hval.y; a1.z += p * hval.z; a1.w += p * hval.w;
            }
        }
#pragma unroll
        for (int r = 0; r < 2; ++r) {
            float4 a = r ? a1 : a0;
            int j = i0 - 32 + mb + r;
            int jc = min(max(j, 0), S_LEN - 1);
            float4 vv = *(const float4*)(v + (size_t)jc * E_DIM + c0 + ci * 4);
            float4 o;
            o.x = 0.9f * a.x + 0.1f * vv.x;
            o.y = 0.9f * a.y + 0.1f * vv.y;
            o.z = 0.9f * a.z + 0.1f * vv.z;
            o.w = 0.9f * a.w + 0.1f * vv.w;
            *(float4*)(h1 + (mb + r) * 36 + ci * 4) = o;
        }
    }
    __syncthreads();

    // ---- step B: out row g ----
    {
        float4 a = {0,0,0,0};
        for (int off = 0; off < NOFF; ++off) {
            float4 hval = *(const float4*)(h1 + (g + off) * 36 + ci * 4);
            float p = ps[(g + 32) * NOFF + off];
            a.x += p * hval.x; a.y += p * hval.y; a.z += p * hval.z; a.w += p * hval.w;
        }
        size_t base = (size_t)(i0 + g) * E_DIM + c0 + ci * 4;
        float4 vv = *(const float4*)(v + base);
        float4 o;
        o.x = 0.9f * a.x + 0.1f * vv.x;
        o.y = 0.9f * a.y + 0.1f * vv.y;
        o.z = 0.9f * a.z + 0.1f * vv.z;
        o.w = 0.9f * a.w + 0.1f * vv.w;
        *(float4*)(hout + base) = o;
    }
}

// ---------------------------------------------------------------------------
// oln (proven R4/R6): y = h@Wo + bo + x, then LayerNorm, fused.
// Block = 16 rows x 512 cols, 512 threads (8 waves x 4 n-tiles). 128 blocks.
// ---------------------------------------------------------------------------
__global__ __launch_bounds__(512)
void oln(const float* __restrict__ hsrc, const float* __restrict__ Wo,
         const float* __restrict__ bo, const float* __restrict__ x,
         const float* __restrict__ g, const float* __restrict__ lb,
         float* __restrict__ out)
{
    __shared__ unsigned short As[16 * 40];
    __shared__ unsigned short Bs[512 * 40];
    __shared__ float rsum[8][16], rsq[8][16];
    const int tid = threadIdx.x;
    const int lane = tid & 63, wave = tid >> 6;
    const int quad = lane >> 4, l16 = lane & 15;
    const int m0 = blockIdx.x * 16;
    const int n = tid;

    f32x4 acc[4];
#pragma unroll
    for (int t = 0; t < 4; ++t) acc[t] = (f32x4){0.f,0.f,0.f,0.f};

    for (int kk = 0; kk < E_DIM; kk += 32) {
        float4 av;
        if (tid < 128)
            av = *(const float4*)(hsrc + (size_t)(m0 + (tid >> 3)) * E_DIM + kk + (tid & 7) * 4);
        float bcol[32];
#pragma unroll
        for (int j = 0; j < 32; ++j)
            bcol[j] = Wo[(size_t)(kk + j) * E_DIM + n];
        __syncthreads();
        if (tid < 128) {
            uint2 ap; ap.x = pk2(av.x, av.y); ap.y = pk2(av.z, av.w);
            *(uint2*)(As + (tid >> 3) * 40 + (tid & 7) * 4) = ap;
        }
#pragma unroll
        for (int t = 0; t < 4; ++t) {
            uint4 bp;
            bp.x = pk2(bcol[t*8+0], bcol[t*8+1]); bp.y = pk2(bcol[t*8+2], bcol[t*8+3]);
            bp.z = pk2(bcol[t*8+4], bcol[t*8+5]); bp.w = pk2(bcol[t*8+6], bcol[t*8+7]);
            *(uint4*)(Bs + n * 40 + t * 8) = bp;
        }
        __syncthreads();
        short8 fa = *(const short8*)(As + l16 * 40 + quad * 8);
#pragma unroll
        for (int nt = 0; nt < 4; ++nt) {
            short8 fb = *(const short8*)(Bs + (wave * 64 + nt * 16 + l16) * 40 + quad * 8);
            acc[nt] = __builtin_amdgcn_mfma_f32_16x16x32_bf16(fa, fb, acc[nt], 0, 0, 0);
        }
    }

    float s[4] = {0.f,0.f,0.f,0.f}, s2[4] = {0.f,0.f,0.f,0.f};
#pragma unroll
    for (int nt = 0; nt < 4; ++nt) {
        int nc = wave * 64 + nt * 16 + l16;
        float bv = bo[nc];
#pragma unroll
        for (int r = 0; r < 4; ++r) {
            int m = m0 + quad * 4 + r;
            float vl = acc[nt][r] + bv + x[(size_t)m * E_DIM + nc];
            acc[nt][r] = vl;
            s[r] += vl; s2[r] += vl * vl;
        }
    }
#pragma unroll
    for (int o = 1; o < 16; o <<= 1) {
#pragma unroll
        for (int r = 0; r < 4; ++r) {
            s[r]  += __shfl_xor(s[r], o, 64);
            s2[r] += __shfl_xor(s2[r], o, 64);
        }
    }
    if (l16 == 0) {
#pragma unroll
        for (int r = 0; r < 4; ++r) {
            rsum[wave][quad * 4 + r] = s[r];
            rsq[wave][quad * 4 + r]  = s2[r];
        }
    }
    __syncthreads();
    float mu[4], rs[4];
#pragma unroll
    for (int r = 0; r < 4; ++r) {
        int rl = quad * 4 + r;
        float tot = 0.f, tot2 = 0.f;
#pragma unroll
        for (int w = 0; w < 8; ++w) { tot += rsum[w][rl]; tot2 += rsq[w][rl]; }
        float m_ = tot * (1.f / 512.f);
        float var = tot2 * (1.f / 512.f) - m_ * m_;
        mu[r] = m_; rs[r] = rsqrtf(var + 1e-12f);
    }
#pragma unroll
    for (int nt = 0; nt < 4; ++nt) {
        int nc = wave * 64 + nt * 16 + l16;
        float gv = g[nc], bbv = lb[nc];
#pragma unroll
        for (int r = 0; r < 4; ++r) {
            int m = m0 + quad * 4 + r;
            out[(size_t)m * E_DIM + nc] = (acc[nt][r] - mu[r]) * rs[r] * gv + bbv;
        }
    }
}

// ---------------------------------------------------------------------------
extern "C" void kernel_launch(void* const* d_in, const int* in_sizes, int n_in,
                              void* d_out, int out_size, void* d_ws, size_t ws_size,
                              hipStream_t stream)
{
    const float* x     = (const float*)d_in[0];
    const float* amask = (const float*)d_in[1];
    const float* Wq = (const float*)d_in[4];
    const float* bq = (const float*)d_in[5];
    const float* Wk = (const float*)d_in[6];
    const float* bk = (const float*)d_in[7];
    const float* Wv = (const float*)d_in[8];
    const float* bv = (const float*)d_in[9];
    const float* Wo = (const float*)d_in[10];
    const float* bo = (const float*)d_in[11];
    const float* lng = (const float*)d_in[12];
    const float* lnb = (const float*)d_in[13];
    float* out = (float*)d_out;

    float* ws = (float*)d_ws;
    float* q  = ws;
    float* k  = ws + (size_t)NE;
    float* v  = ws + (size_t)2 * NE;
    float* P  = ws + (size_t)3 * NE;
    float* hA = ws + (size_t)3 * NE + PN;
    float* hB = hA + (size_t)NE;

    qkv_gemm<<<dim3(8, 32, 3), 256, 0, stream>>>(x, Wq, bq, Wk, bk, Wv, bv, q, k, v);

    scores_d1<<<dim3(64, 8), 256, 0, stream>>>(q, k, v, amask, P, hA);  // P + step 1

    diffuse2c<<<dim3(32, 16), 512, 0, stream>>>(hA, v, P, hB);  // steps 2-3
    diffuse2c<<<dim3(32, 16), 512, 0, stream>>>(hB, v, P, hA);  // steps 4-5

    oln<<<128, 512, 0, stream>>>(hA, Wo, bo, x, lng, lnb, out);
}